// Round 17
// baseline (296.660 us; speedup 1.0000x reference)
//
#include <hip/hip_runtime.h>
#include <stdint.h>

#define S_DIM 2048
#define B_DIM 2
#define D_DIM 2048
#define H_DIM 16
#define C_DIM 128
#define M_DIM 4096   // S*B rows, row = s*B + b

typedef __bf16 bf16x8 __attribute__((ext_vector_type(8)));
typedef float f32x4 __attribute__((ext_vector_type(4)));
typedef unsigned short u16x4 __attribute__((ext_vector_type(4)));
typedef unsigned short u16x8 __attribute__((ext_vector_type(8)));

__device__ __forceinline__ float bf2f(unsigned short u) {
    union { unsigned int i; float f; } c; c.i = ((unsigned int)u) << 16; return c.f;
}
__device__ __forceinline__ unsigned short f2bf(float f) {
    union { float f; unsigned int i; } c; c.f = f;
    unsigned int r = c.i + 0x7FFFu + ((c.i >> 16) & 1u);  // RTN-even
    return (unsigned short)(r >> 16);
}

// ------- x + 4 weight matrices fp32->bf16 + RoPE cos/sin tables, ONE launch -------
__global__ void cast_all_k(const float* __restrict__ x,
                           const float* __restrict__ w0, const float* __restrict__ w1,
                           const float* __restrict__ w2, const float* __restrict__ w3,
                           const float* __restrict__ freqs,
                           unsigned short* __restrict__ xb, unsigned short* __restrict__ wb,
                           float* __restrict__ ctab, float* __restrict__ stab) {
    const int nx4 = (M_DIM * D_DIM) / 4;   // 2 * 2^20
    const int nw4 = (D_DIM * D_DIM) / 4;   // 2^20
    const int nr4 = (S_DIM * C_DIM) / 4;   // 65536
    const int total = nx4 + 4 * nw4 + nr4;
    int stride = gridDim.x * blockDim.x;
    for (int i = blockIdx.x * blockDim.x + threadIdx.x; i < total; i += stride) {
        if (i < nx4 + 4 * nw4) {
            const float* src; unsigned short* dst; int idx;
            if (i < nx4) { src = x; dst = xb; idx = i; }
            else {
                int j = i - nx4;
                int sel = j >> 20;
                idx = j & (nw4 - 1);
                src = (sel == 0) ? w0 : (sel == 1) ? w1 : (sel == 2) ? w2 : w3;
                dst = wb + (size_t)sel * (size_t)D_DIM * D_DIM;
            }
            float4 v = reinterpret_cast<const float4*>(src)[idx];
            ushort4 o;
            o.x = f2bf(v.x); o.y = f2bf(v.y); o.z = f2bf(v.z); o.w = f2bf(v.w);
            reinterpret_cast<ushort4*>(dst)[idx] = o;
        } else {
            const int j = i - nx4 - 4 * nw4;
            float4 f = reinterpret_cast<const float4*>(freqs)[j];
            float4 cv, sv;
            cv.x = cosf(f.x); cv.y = cosf(f.y); cv.z = cosf(f.z); cv.w = cosf(f.w);
            sv.x = sinf(f.x); sv.y = sinf(f.y); sv.z = sinf(f.z); sv.w = sinf(f.w);
            reinterpret_cast<float4*>(ctab)[j] = cv;
            reinterpret_cast<float4*>(stab)[j] = sv;
        }
    }
}

// ========== GEMM (QKV): r13 form + spread A-staging — BM=256 x BN=384, BK=64 ====
// B-frag reads before the phase barrier; A-frag reads INSIDE the MFMA cluster
// (compiler-managed lgkmcnt interleave — r14 proved pinning this hurts here).
// A(T+1) staged in halves at ph0 and ph1 (evens the memory-issue pipe);
// B(T+2) must stay at ph3 (ldsB[T&1] still read at ph2). vmcnt(6) unchanged:
// per-tile issue order [A2,A2,B6] -> 10 oldest = B(T+1)6+A(T+1)4 complete.
template <typename OutT, int BN>
__global__ __launch_bounds__(512) void gemm8_k(
    const unsigned short* __restrict__ A,
    const unsigned short* __restrict__ Bm,
    OutT* __restrict__ C,
    int M, int N, int K)
{
    constexpr int NFR = BN / 64;        // n-frags per wave (6 for BN=384)
    constexpr int WNS = BN / 4;         // per-wave n span (96)
    constexpr int BCH = BN / 64 * 512;  // B chunks per tile (3072 for 384)
    __shared__ __align__(16) unsigned short ldsA[2][256 * 64];   // 64 KiB
    __shared__ __align__(16) unsigned short ldsB[2][BN * 64];    // 96 KiB @384

    const int tid  = threadIdx.x;
    const int wave = tid >> 6;
    const int lane = tid & 63;
    const int wm = wave >> 2;           // 0..1 (M, 128 rows each)
    const int wn = wave & 3;            // 0..3 (N, WNS cols each)
    const int g  = lane >> 4;           // k-chunk group 0..3
    const int ro = lane & 15;

    // T1: bijective XCD swizzle (nwg % 8 == 0)
    const int nwg = gridDim.x * gridDim.y;
    int lin = blockIdx.y * gridDim.x + blockIdx.x;
    lin = (lin & 7) * (nwg >> 3) + (lin >> 3);
    const int brow = (lin % gridDim.x) * 256;
    const int bcol = (lin / gridDim.x) * BN;
    const int NT = K >> 6;              // K-tiles of 64

    const unsigned short* As = A  + (size_t)brow * K;
    const unsigned short* Bs = Bm + (size_t)bcol * K;

    f32x4 acc[8][NFR] = {};

    // stage half of A K-tile T (half = 0: rows 0..128, 1: rows 128..256)
    auto stageA = [&](int T, int half) {
        const int buf = T & 1;
        #pragma unroll
        for (int j = 0; j < 2; ++j) {
            const int slot = (half * 2 + j) * 512 + tid;
            const int row = slot >> 3, c = slot & 7;
            __builtin_amdgcn_global_load_lds(
                (const __attribute__((address_space(1))) void*)(
                    As + (size_t)row * K + T * 64 + ((c ^ (row & 7)) << 3)),
                (__attribute__((address_space(3))) void*)(
                    &ldsA[buf][((half * 2 + j) * 512 + wave * 64) * 8]),
                16, 0, 0);
        }
    };
    auto stageB = [&](int T) {
        const int buf = T & 1;
        #pragma unroll
        for (int j = 0; j < BCH / 512; ++j) {
            const int slot = j * 512 + tid;
            const int row = slot >> 3, c = slot & 7;
            __builtin_amdgcn_global_load_lds(
                (const __attribute__((address_space(1))) void*)(
                    Bs + (size_t)row * K + T * 64 + ((c ^ (row & 7)) << 3)),
                (__attribute__((address_space(3))) void*)(
                    &ldsB[buf][(j * 512 + wave * 64) * 8]),
                16, 0, 0);
        }
    };

    auto rdA = [&](int buf, int mi, int ks) -> bf16x8 {
        const int row = wm * 128 + mi * 16 + ro;
        return *reinterpret_cast<const bf16x8*>(
            &ldsA[buf][row * 64 + (((ks * 4 + g) ^ (row & 7)) << 3)]);
    };
    auto rdB = [&](int buf, int ni, int ks) -> bf16x8 {
        const int row = wn * WNS + ni * 16 + ro;
        return *reinterpret_cast<const bf16x8*>(
            &ldsB[buf][row * 64 + (((ks * 4 + g) ^ (row & 7)) << 3)]);
    };

    // prologue (FIFO order): B(0), A(0), B(1)
    stageB(0);
    stageA(0, 0);
    stageA(0, 1);
    stageB(1);
    asm volatile("s_waitcnt vmcnt(6)" ::: "memory");
    __builtin_amdgcn_s_barrier();

    for (int T = 0; T < NT; ++T) {
        const int buf = T & 1;
        bf16x8 bfr[NFR];

        // ---- ph0: (mq0, ks0), read B(ks0), stage A(T+1) half 0 ----
        #pragma unroll
        for (int i = 0; i < NFR; ++i) bfr[i] = rdB(buf, i, 0);
        if (T + 1 < NT) stageA(T + 1, 0);
        __builtin_amdgcn_s_barrier();
        __builtin_amdgcn_s_setprio(1);
        #pragma unroll
        for (int mi = 0; mi < 4; ++mi) {
            bf16x8 af = rdA(buf, mi, 0);
            #pragma unroll
            for (int ni = 0; ni < NFR; ++ni)
                acc[mi][ni] = __builtin_amdgcn_mfma_f32_16x16x32_bf16(af, bfr[ni], acc[mi][ni], 0, 0, 0);
        }
        __builtin_amdgcn_s_setprio(0);
        __builtin_amdgcn_s_barrier();

        // ---- ph1: (mq1, ks0), stage A(T+1) half 1 ----
        if (T + 1 < NT) stageA(T + 1, 1);
        __builtin_amdgcn_s_setprio(1);
        #pragma unroll
        for (int mi = 0; mi < 4; ++mi) {
            bf16x8 af = rdA(buf, 4 + mi, 0);
            #pragma unroll
            for (int ni = 0; ni < NFR; ++ni)
                acc[4 + mi][ni] = __builtin_amdgcn_mfma_f32_16x16x32_bf16(af, bfr[ni], acc[4 + mi][ni], 0, 0, 0);
        }
        __builtin_amdgcn_s_setprio(0);
        __builtin_amdgcn_s_barrier();

        // ---- ph2: (mq0, ks1), read B(ks1) ----
        #pragma unroll
        for (int i = 0; i < NFR; ++i) bfr[i] = rdB(buf, i, 1);
        __builtin_amdgcn_s_barrier();
        __builtin_amdgcn_s_setprio(1);
        #pragma unroll
        for (int mi = 0; mi < 4; ++mi) {
            bf16x8 af = rdA(buf, mi, 1);
            #pragma unroll
            for (int ni = 0; ni < NFR; ++ni)
                acc[mi][ni] = __builtin_amdgcn_mfma_f32_16x16x32_bf16(af, bfr[ni], acc[mi][ni], 0, 0, 0);
        }
        __builtin_amdgcn_s_setprio(0);
        __builtin_amdgcn_s_barrier();

        // ---- ph3: (mq1, ks1), stage B(T+2), counted vmcnt ----
        if (T + 2 < NT) stageB(T + 2);
        if (T + 1 < NT) {
            if (T + 2 < NT) asm volatile("s_waitcnt vmcnt(6)" ::: "memory");
            else            asm volatile("s_waitcnt vmcnt(0)" ::: "memory");
        }
        __builtin_amdgcn_s_setprio(1);
        #pragma unroll
        for (int mi = 0; mi < 4; ++mi) {
            bf16x8 af = rdA(buf, 4 + mi, 1);
            #pragma unroll
            for (int ni = 0; ni < NFR; ++ni)
                acc[4 + mi][ni] = __builtin_amdgcn_mfma_f32_16x16x32_bf16(af, bfr[ni], acc[4 + mi][ni], 0, 0, 0);
        }
        __builtin_amdgcn_s_setprio(0);
        __builtin_amdgcn_s_barrier();
    }

    // epilogue: C/D layout col=lane&15, row=(lane>>4)*4+reg  (m89-verified)
    const int rg = g * 4;
    #pragma unroll
    for (int mi = 0; mi < 8; ++mi) {
        #pragma unroll
        for (int r = 0; r < 4; ++r) {
            const int row = brow + wm * 128 + mi * 16 + rg + r;
            const size_t base = (size_t)row * N + bcol + wn * WNS;
            #pragma unroll
            for (int ni = 0; ni < NFR; ++ni) {
                float v = acc[mi][ni][r];
                if constexpr (sizeof(OutT) == 2) C[base + ni * 16 + ro] = f2bf(v);
                else                             C[base + ni * 16 + ro] = v;
            }
        }
    }
}

// ========== GEMM v4 (out-proj): r13 PINNED form — BM=128 x BN=256, BK=64 ========
// r15 A/B: un-pinning this kernel cost ~5us; the pinned schedule wins here.
template <typename OutT>
__global__ __launch_bounds__(512) void gemm_v4_k(
    const unsigned short* __restrict__ A,
    const unsigned short* __restrict__ Bm,
    OutT* __restrict__ C,
    int M, int N, int K)
{
    constexpr int ATILE = 128 * 64;
    constexpr int BTILE = 256 * 64;
    __shared__ __align__(16) unsigned short ldsA[3 * ATILE];
    __shared__ __align__(16) unsigned short ldsB[3 * BTILE];

    const int tid  = threadIdx.x;
    const int wave = tid >> 6;
    const int lane = tid & 63;
    const int wm = wave >> 2;
    const int wn = wave & 3;
    const int g  = lane >> 4;
    const int ro = lane & 15;

    const int nwg = gridDim.x * gridDim.y;
    int lin = blockIdx.y * gridDim.x + blockIdx.x;
    lin = (lin & 7) * (nwg >> 3) + (lin >> 3);
    const int brow = (lin % gridDim.x) * 128;
    const int bcol = (lin / gridDim.x) * 256;
    const int NT = K >> 6;

    const unsigned short* As = A  + (size_t)brow * K;
    const unsigned short* Bs = Bm + (size_t)bcol * K;

    f32x4 acc[4][4] = {};

    auto stage = [&](int buf, int t) {
        #pragma unroll
        for (int j = 0; j < 2; ++j) {
            const int slot = j * 512 + tid;
            const int row = slot >> 3, c = slot & 7;
            __builtin_amdgcn_global_load_lds(
                (const __attribute__((address_space(1))) void*)(
                    As + (size_t)row * K + t * 64 + ((c ^ (row & 7)) << 3)),
                (__attribute__((address_space(3))) void*)(
                    ldsA + buf * ATILE + (j * 512 + wave * 64) * 8),
                16, 0, 0);
        }
        #pragma unroll
        for (int j = 0; j < 4; ++j) {
            const int slot = j * 512 + tid;
            const int row = slot >> 3, c = slot & 7;
            __builtin_amdgcn_global_load_lds(
                (const __attribute__((address_space(1))) void*)(
                    Bs + (size_t)row * K + t * 64 + ((c ^ (row & 7)) << 3)),
                (__attribute__((address_space(3))) void*)(
                    ldsB + buf * BTILE + (j * 512 + wave * 64) * 8),
                16, 0, 0);
        }
    };

    auto rdA = [&](int buf, int mi, int ks) -> bf16x8 {
        const int row = wm * 64 + mi * 16 + ro;
        const int c = (ks * 4 + g) ^ (row & 7);
        return *reinterpret_cast<const bf16x8*>(ldsA + buf * ATILE + row * 64 + c * 8);
    };
    auto rdB = [&](int buf, int ni, int ks) -> bf16x8 {
        const int row = wn * 64 + ni * 16 + ro;
        const int c = (ks * 4 + g) ^ (row & 7);
        return *reinterpret_cast<const bf16x8*>(ldsB + buf * BTILE + row * 64 + c * 8);
    };

    stage(0, 0);
    stage(1, 1);
    asm volatile("s_waitcnt vmcnt(6)" ::: "memory");
    __builtin_amdgcn_s_barrier();

    int cb = 0;
    for (int t = 0; t < NT; ++t) {
        #pragma unroll
        for (int ks = 0; ks < 2; ++ks) {
            bf16x8 af[4], bf[4];
            #pragma unroll
            for (int i = 0; i < 4; ++i) af[i] = rdA(cb, i, ks);
            #pragma unroll
            for (int i = 0; i < 4; ++i) bf[i] = rdB(cb, i, ks);
            if (ks == 0) {
                if (t + 2 < NT) stage((cb == 0) ? 2 : cb - 1, t + 2);
            } else {
                if (t + 2 < NT) asm volatile("s_waitcnt vmcnt(6)" ::: "memory");
                else            asm volatile("s_waitcnt vmcnt(0)" ::: "memory");
            }
            __builtin_amdgcn_s_barrier();
            asm volatile("s_waitcnt lgkmcnt(0)" ::: "memory");
            __builtin_amdgcn_sched_barrier(0);
            __builtin_amdgcn_s_setprio(1);
            #pragma unroll
            for (int mi = 0; mi < 4; ++mi)
                #pragma unroll
                for (int ni = 0; ni < 4; ++ni)
                    acc[mi][ni] = __builtin_amdgcn_mfma_f32_16x16x32_bf16(
                        af[mi], bf[ni], acc[mi][ni], 0, 0, 0);
            __builtin_amdgcn_s_setprio(0);
            __builtin_amdgcn_s_barrier();
        }
        cb = (cb == 2) ? 0 : cb + 1;
    }

    const int rg = g * 4;
    #pragma unroll
    for (int mi = 0; mi < 4; ++mi) {
        #pragma unroll
        for (int r = 0; r < 4; ++r) {
            const int row = brow + wm * 64 + mi * 16 + rg + r;
            const size_t base = (size_t)row * N + bcol + wn * 64;
            #pragma unroll
            for (int ni = 0; ni < 4; ++ni) {
                float v = acc[mi][ni][r];
                if constexpr (sizeof(OutT) == 2) C[base + ni * 16 + ro] = f2bf(v);
                else                             C[base + ni * 16 + ro] = v;
            }
        }
    }
}

// ---------------- per-head RMSNorm + RoPE on Q AND K in one launch ----------------
__global__ __launch_bounds__(256) void qk_post2_k(
    const unsigned short* __restrict__ rawQKV, int ld,
    const float* __restrict__ q_scale, const float* __restrict__ k_scale,
    const float* __restrict__ ctab, const float* __restrict__ stab,
    unsigned short* __restrict__ Qb, unsigned short* __restrict__ Kb,
    float inv_scale)
{
    const int isK = blockIdx.y;
    const unsigned short* raw = rawQKV + (isK ? D_DIM : 0);
    const float* wscale = isK ? k_scale : q_scale;
    unsigned short* outp = isK ? Kb : Qb;
    const float post_mul = isK ? 1.0f : inv_scale;

    const int gw = blockIdx.x * 4 + (threadIdx.x >> 6);
    const int lane = threadIdx.x & 63;
    const int m = gw >> 4;
    const int h = gw & 15;
    const int s = m >> 1, b = m & 1;
    const int c0 = lane * 2;

    const unsigned short* src = raw + (size_t)m * ld + h * C_DIM + c0;
    unsigned int packed = *reinterpret_cast<const unsigned int*>(src);
    float x0 = bf2f((unsigned short)(packed & 0xFFFF));
    float x1 = bf2f((unsigned short)(packed >> 16));

    float ss = x0 * x0 + x1 * x1;
    #pragma unroll
    for (int off = 32; off; off >>= 1) ss += __shfl_xor(ss, off);
    const float rs = rsqrtf(ss * (1.0f / C_DIM) + 1e-6f);

    float n0 = x0 * rs * wscale[c0];
    float n1 = x1 * rs * wscale[c0 + 1];
    float p0 = __shfl_xor(n0, 32);
    float p1 = __shfl_xor(n1, 32);
    const float sgn = (lane < 32) ? -1.0f : 1.0f;
    const float* cp = ctab + (size_t)s * C_DIM + c0;
    const float* sp = stab + (size_t)s * C_DIM + c0;
    float o0 = (n0 * cp[0] + sgn * p0 * sp[0]) * post_mul;
    float o1 = (n1 * cp[1] + sgn * p1 * sp[1]) * post_mul;

    unsigned int opk = (unsigned int)f2bf(o0) | ((unsigned int)f2bf(o1) << 16);
    *reinterpret_cast<unsigned int*>(
        outp + ((size_t)(b * H_DIM + h) * S_DIM + s) * C_DIM + c0) = opk;
}

// ---------------- V relayout+transpose -> Vt [b*H+h][C][S] ----------------
__global__ __launch_bounds__(256) void v_transpose_k(
    const unsigned short* __restrict__ raw, int ld, int colbase,
    unsigned short* __restrict__ Vt)
{
    __shared__ __align__(16) unsigned short tile[64][136];  // +8 pad
    const int bh = blockIdx.y;
    const int b = bh >> 4, h = bh & 15;
    const int sbase = blockIdx.x * 64;
    const int t = threadIdx.x;

    {
        const int s = t >> 2, cq = (t & 3) * 32;
        const unsigned short* src = raw + (size_t)((sbase + s) * B_DIM + b) * ld + colbase + h * C_DIM + cq;
        #pragma unroll
        for (int j = 0; j < 4; ++j) {
            u16x8 v = *reinterpret_cast<const u16x8*>(src + j * 8);
            *reinterpret_cast<u16x8*>(&tile[s][cq + j * 8]) = v;
        }
    }
    __syncthreads();
    {
        const int c = t >> 1, sh = (t & 1) * 32;
        unsigned short* dst = Vt + ((size_t)bh * C_DIM + c) * S_DIM + sbase + sh;
        #pragma unroll
        for (int j = 0; j < 32; j += 8) {
            u16x8 o;
            #pragma unroll
            for (int e = 0; e < 8; ++e) o[e] = tile[sh + j + e][c];
            *reinterpret_cast<u16x8*>(dst + j) = o;
        }
    }
}

// ---------------- flash attention v8: swapped QK^T, KVBLK=128, 160KB LDS -------
__global__ __launch_bounds__(512, 1) void attn_k(
    const unsigned short* __restrict__ Qb,
    const unsigned short* __restrict__ Kb,
    const unsigned short* __restrict__ Vt,
    unsigned short* __restrict__ Ao)          // [M][D], row = s*B+b, col = h*C+c
{
    __shared__ __align__(16) unsigned short ldsK[2][128 * 128];  // 64 KiB
    __shared__ __align__(16) unsigned short ldsV[2][128 * 128];  // 64 KiB
    __shared__ __align__(16) unsigned short plds[8][32 * 64];    // 32 KiB

    const int bh = blockIdx.y;
    const int wave = threadIdx.x >> 6;
    const int lane = threadIdx.x & 63;
    const int qbase = blockIdx.x * 256 + wave * 32;
    const int g  = lane >> 4;
    const int ro = lane & 15;
    const int ko = g * 8;
    const int rg = g * 4;

    const unsigned short* Q  = Qb + (size_t)bh * S_DIM * C_DIM;
    const unsigned short* Km = Kb + (size_t)bh * S_DIM * C_DIM;
    const unsigned short* V  = Vt + (size_t)bh * C_DIM * S_DIM;
    unsigned short* pw = &plds[wave][0];

    bf16x8 qf[2][4];
    #pragma unroll
    for (int mq = 0; mq < 2; ++mq)
        #pragma unroll
        for (int kf = 0; kf < 4; ++kf)
            qf[mq][kf] = *reinterpret_cast<const bf16x8*>(
                Q + (size_t)(qbase + mq * 16 + ro) * C_DIM + kf * 32 + ko);

    bf16x8 ones;
    #pragma unroll
    for (int e = 0; e < 8; ++e) ones[e] = (__bf16)1.0f;

    auto stage = [&](int bufi, int kb) {
        #pragma unroll
        for (int j = 0; j < 4; ++j) {
            const int idx = (wave * 4 + j) * 64 + lane;
            const int row = idx >> 4, ch = idx & 15;
            const int sch = (ch & 8) | ((ch ^ row) & 7);
            __builtin_amdgcn_global_load_lds(
                (const __attribute__((address_space(1))) void*)(
                    Km + (size_t)(kb + row) * C_DIM + sch * 8),
                (__attribute__((address_space(3))) void*)(
                    &ldsK[bufi][(wave * 4 + j) * 512]),
                16, 0, 0);
            __builtin_amdgcn_global_load_lds(
                (const __attribute__((address_space(1))) void*)(
                    V + (size_t)row * S_DIM + kb + sch * 8),
                (__attribute__((address_space(3))) void*)(
                    &ldsV[bufi][(wave * 4 + j) * 512]),
                16, 0, 0);
        }
    };

    f32x4 of[2][8] = {};
    f32x4 osum[2] = {};
    float mrow[2] = {-1e30f, -1e30f};

    stage(0, 0);
    asm volatile("s_waitcnt vmcnt(0)" ::: "memory");
    __syncthreads();

    int cur = 0;
    for (int kb = 0; kb < S_DIM; kb += 128) {
        if (kb + 128 < S_DIM) stage(cur ^ 1, kb + 128);

        // ---- QK^T swapped: s4[mq][nc][r] = S[q=mq*16+ro][kv=nc*16+4g+r] ----
        f32x4 s4[2][8] = {};
        __builtin_amdgcn_s_setprio(1);
        #pragma unroll
        for (int nc = 0; nc < 8; ++nc) {
            const int r_loc = nc * 16 + ro;
            bf16x8 kfr[4];
            #pragma unroll
            for (int kf = 0; kf < 4; ++kf) {
                const int c = kf * 4 + g;
                const int sch = (c & 8) | ((c ^ r_loc) & 7);
                kfr[kf] = *reinterpret_cast<const bf16x8*>(&ldsK[cur][r_loc * 128 + sch * 8]);
            }
            #pragma unroll
            for (int mq = 0; mq < 2; ++mq)
                #pragma unroll
                for (int kf = 0; kf < 4; ++kf)
                    s4[mq][nc] = __builtin_amdgcn_mfma_f32_16x16x32_bf16(
                        kfr[kf], qf[mq][kf], s4[mq][nc], 0, 0, 0);
        }
        __builtin_amdgcn_s_setprio(0);

        // ---- per-lane row max ----
        float mx[2];
        #pragma unroll
        for (int mq = 0; mq < 2; ++mq) {
            float m0 = fmaxf(fmaxf(s4[mq][0][0], s4[mq][0][1]), fmaxf(s4[mq][0][2], s4[mq][0][3]));
            #pragma unroll
            for (int nc = 1; nc < 8; ++nc) {
                float mn = fmaxf(fmaxf(s4[mq][nc][0], s4[mq][nc][1]),
                                 fmaxf(s4[mq][nc][2], s4[mq][nc][3]));
                m0 = fmaxf(m0, mn);
            }
            m0 = fmaxf(m0, __shfl_xor(m0, 16));
            m0 = fmaxf(m0, __shfl_xor(m0, 32));
            mx[mq] = m0;
        }

        // ---- defer-max: rescale rarely; broadcast per-q factors via shfl ----
        if (__any(fmaxf(mx[0] - mrow[0], mx[1] - mrow[1]) > 8.0f)) {
            #pragma unroll
            for (int mq = 0; mq < 2; ++mq) {
                float mnew = fmaxf(mrow[mq], mx[mq]);
                float dm = mrow[mq] - mnew;
                mrow[mq] = mnew;
                #pragma unroll
                for (int r = 0; r < 4; ++r) {
                    float dr = __shfl(dm, (lane & 48) | (rg + r));
                    float rs = __expf(dr);
                    osum[mq][r] *= rs;
                    #pragma unroll
                    for (int nf = 0; nf < 8; ++nf) of[mq][nf][r] *= rs;
                }
            }
        }

        // ---- per kv-half: P -> per-wave LDS (sequential reuse) -> PV ----
        #pragma unroll
        for (int h = 0; h < 2; ++h) {
            #pragma unroll
            for (int mq = 0; mq < 2; ++mq) {
                const int qrow = mq * 16 + ro;
                #pragma unroll
                for (int ncl = 0; ncl < 4; ++ncl) {
                    u16x4 pk;
                    #pragma unroll
                    for (int r = 0; r < 4; ++r)
                        pk[r] = f2bf(__expf(s4[mq][4 * h + ncl][r] - mrow[mq]));
                    const int chunk = 2 * ncl + (g >> 1);
                    *reinterpret_cast<u16x4*>(
                        &pw[qrow * 64 + ((chunk ^ (ro & 7)) << 3) + 4 * (g & 1)]) = pk;
                }
            }
            __asm__ volatile("" ::: "memory");

            __builtin_amdgcn_s_setprio(1);
            #pragma unroll
            for (int ksl = 0; ksl < 2; ++ksl) {
                bf16x8 pa[2];
                #pragma unroll
                for (int mq = 0; mq < 2; ++mq) {
                    const int qrow = mq * 16 + ro;
                    pa[mq] = *reinterpret_cast<const bf16x8*>(
                        &pw[qrow * 64 + (((ksl * 4 + g) ^ (ro & 7)) << 3)]);
                }
                const int ksg = h * 2 + ksl;   // global 32-kv slice 0..3
                #pragma unroll
                for (int nf = 0; nf < 8; ++nf) {
                    const int vr = nf * 16 + ro;
                    const int c2 = ksg * 4 + g;
                    const int sch = (c2 & 8) | ((c2 ^ vr) & 7);
                    bf16x8 vf = *reinterpret_cast<const bf16x8*>(&ldsV[cur][vr * 128 + sch * 8]);
                    #pragma unroll
                    for (int mq = 0; mq < 2; ++mq)
                        of[mq][nf] = __builtin_amdgcn_mfma_f32_16x16x32_bf16(pa[mq], vf, of[mq][nf], 0, 0, 0);
                }
                #pragma unroll
                for (int mq = 0; mq < 2; ++mq)
                    osum[mq] = __builtin_amdgcn_mfma_f32_16x16x32_bf16(pa[mq], ones, osum[mq], 0, 0, 0);
            }
            __builtin_amdgcn_s_setprio(0);
            __asm__ volatile("" ::: "memory");
        }

        asm volatile("s_waitcnt vmcnt(0)" ::: "memory");
        __syncthreads();
        cur ^= 1;
    }

    const int b = bh >> 4, h = bh & 15;
    #pragma unroll
    for (int mq = 0; mq < 2; ++mq) {
        #pragma unroll
        for (int r = 0; r < 4; ++r) {
            const float inv_l = 1.0f / osum[mq][r];
            const int srow = qbase + mq * 16 + rg + r;
            unsigned short* dst = Ao + (size_t)(srow * B_DIM + b) * D_DIM + h * C_DIM;
            #pragma unroll
            for (int nf = 0; nf < 8; ++nf)
                dst[nf * 16 + ro] = f2bf(of[mq][nf][r] * inv_l);
        }
    }
}

extern "C" void kernel_launch(void* const* d_in, const int* in_sizes, int n_in,
                              void* d_out, int out_size, void* d_ws, size_t ws_size,
                              hipStream_t stream) {
    const float* x       = (const float*)d_in[0];
    const float* rope    = (const float*)d_in[1];
    const float* Wq      = (const float*)d_in[2];
    const float* Wk      = (const float*)d_in[3];
    const float* Wv      = (const float*)d_in[4];
    const float* Wo      = (const float*)d_in[5];
    const float* q_scale = (const float*)d_in[6];
    const float* k_scale = (const float*)d_in[7];
    float* out = (float*)d_out;

    char* w = (char*)d_ws;
    size_t off = 0;
    auto alloc = [&](size_t bytes) {
        char* p = w + off; off += (bytes + 255) & ~(size_t)255; return p;
    };
    unsigned short* xb   = (unsigned short*)alloc((size_t)M_DIM * D_DIM * 2);      // 16 MiB
    unsigned short* Wqb  = (unsigned short*)alloc((size_t)4 * D_DIM * D_DIM * 2);  // Wq|Wk|Wv|Wo
    unsigned short* Wob  = Wqb + (size_t)3 * D_DIM * D_DIM;
    unsigned short* rawQKV = (unsigned short*)alloc((size_t)M_DIM * 3 * D_DIM * 2); // [M][6144]
    unsigned short* Qb   = (unsigned short*)alloc((size_t)M_DIM * D_DIM * 2);
    unsigned short* Kb   = (unsigned short*)alloc((size_t)M_DIM * D_DIM * 2);
    unsigned short* Vt   = (unsigned short*)alloc((size_t)M_DIM * D_DIM * 2);
    float* ctab = (float*)alloc((size_t)S_DIM * C_DIM * 4);
    float* stab = (float*)alloc((size_t)S_DIM * C_DIM * 4);
    unsigned short* Ao = rawQKV;  // reuse (rawQKV dead before attention writes)
    (void)ws_size; (void)in_sizes; (void)n_in; (void)out_size;

    const int NQKV = 3 * D_DIM;  // 6144
    const float inv_scale = 0.08838834764831845f;  // 1/sqrt(128)

    cast_all_k<<<2048, 256, 0, stream>>>(x, Wq, Wk, Wv, Wo, rope, xb, Wqb, ctab, stab);

    // fused QKV projection: [4096,2048] x [6144,2048]^T  (256x384 tiles, 16x16=256 blocks EXACT)
    gemm8_k<unsigned short, 384><<<dim3(M_DIM / 256, NQKV / 384), 512, 0, stream>>>(
        xb, Wqb, rawQKV, M_DIM, NQKV, D_DIM);

    qk_post2_k<<<dim3(M_DIM * H_DIM / 4, 2), 256, 0, stream>>>(
        rawQKV, NQKV, q_scale, k_scale, ctab, stab, Qb, Kb, inv_scale);
    v_transpose_k<<<dim3(S_DIM / 64, B_DIM * H_DIM), 256, 0, stream>>>(rawQKV, NQKV, 2 * D_DIM, Vt);

    attn_k<<<dim3(S_DIM / 256, B_DIM * H_DIM), 512, 0, stream>>>(Qb, Kb, Vt, Ao);

    // out projection: [4096,2048] x [2048,2048]^T -> fp32 d_out  (256 blocks exact fill)
    gemm_v4_k<float><<<dim3(M_DIM / 128, D_DIM / 256), 512, 0, stream>>>(
        Ao, Wob, out, M_DIM, D_DIM, D_DIM);
}

// Round 18
// 289.056 us; speedup vs baseline: 1.0263x; 1.0263x over previous
//
#include <hip/hip_runtime.h>
#include <stdint.h>

#define S_DIM 2048
#define B_DIM 2
#define D_DIM 2048
#define H_DIM 16
#define C_DIM 128
#define M_DIM 4096   // S*B rows, row = s*B + b

typedef __bf16 bf16x8 __attribute__((ext_vector_type(8)));
typedef float f32x4 __attribute__((ext_vector_type(4)));
typedef unsigned short u16x4 __attribute__((ext_vector_type(4)));
typedef unsigned short u16x8 __attribute__((ext_vector_type(8)));

__device__ __forceinline__ float bf2f(unsigned short u) {
    union { unsigned int i; float f; } c; c.i = ((unsigned int)u) << 16; return c.f;
}
__device__ __forceinline__ unsigned short f2bf(float f) {
    union { float f; unsigned int i; } c; c.f = f;
    unsigned int r = c.i + 0x7FFFu + ((c.i >> 16) & 1u);  // RTN-even
    return (unsigned short)(r >> 16);
}

// ------- x + 4 weight matrices fp32->bf16 + RoPE cos/sin tables, ONE launch -------
__global__ void cast_all_k(const float* __restrict__ x,
                           const float* __restrict__ w0, const float* __restrict__ w1,
                           const float* __restrict__ w2, const float* __restrict__ w3,
                           const float* __restrict__ freqs,
                           unsigned short* __restrict__ xb, unsigned short* __restrict__ wb,
                           float* __restrict__ ctab, float* __restrict__ stab) {
    const int nx4 = (M_DIM * D_DIM) / 4;   // 2 * 2^20
    const int nw4 = (D_DIM * D_DIM) / 4;   // 2^20
    const int nr4 = (S_DIM * C_DIM) / 4;   // 65536
    const int total = nx4 + 4 * nw4 + nr4;
    int stride = gridDim.x * blockDim.x;
    for (int i = blockIdx.x * blockDim.x + threadIdx.x; i < total; i += stride) {
        if (i < nx4 + 4 * nw4) {
            const float* src; unsigned short* dst; int idx;
            if (i < nx4) { src = x; dst = xb; idx = i; }
            else {
                int j = i - nx4;
                int sel = j >> 20;
                idx = j & (nw4 - 1);
                src = (sel == 0) ? w0 : (sel == 1) ? w1 : (sel == 2) ? w2 : w3;
                dst = wb + (size_t)sel * (size_t)D_DIM * D_DIM;
            }
            float4 v = reinterpret_cast<const float4*>(src)[idx];
            ushort4 o;
            o.x = f2bf(v.x); o.y = f2bf(v.y); o.z = f2bf(v.z); o.w = f2bf(v.w);
            reinterpret_cast<ushort4*>(dst)[idx] = o;
        } else {
            const int j = i - nx4 - 4 * nw4;
            float4 f = reinterpret_cast<const float4*>(freqs)[j];
            float4 cv, sv;
            cv.x = cosf(f.x); cv.y = cosf(f.y); cv.z = cosf(f.z); cv.w = cosf(f.w);
            sv.x = sinf(f.x); sv.y = sinf(f.y); sv.z = sinf(f.z); sv.w = sinf(f.w);
            reinterpret_cast<float4*>(ctab)[j] = cv;
            reinterpret_cast<float4*>(stab)[j] = sv;
        }
    }
}

// ========== GEMM (QKV): r13 form (verified 107us x2) — BM=256 x BN=384, BK=64 ===
// B-frag reads before the phase barrier; A-frag reads INSIDE the MFMA cluster
// (compiler-managed lgkmcnt interleave). stageA whole at ph0, stageB at ph3.
// r14 (pinning) and r17 (spread staging) both regressed — do not perturb.
template <typename OutT, int BN>
__global__ __launch_bounds__(512) void gemm8_k(
    const unsigned short* __restrict__ A,
    const unsigned short* __restrict__ Bm,
    OutT* __restrict__ C,
    int M, int N, int K)
{
    constexpr int NFR = BN / 64;        // n-frags per wave (6 for BN=384)
    constexpr int WNS = BN / 4;         // per-wave n span (96)
    constexpr int BCH = BN / 64 * 512;  // B chunks per tile (3072 for 384)
    __shared__ __align__(16) unsigned short ldsA[2][256 * 64];   // 64 KiB
    __shared__ __align__(16) unsigned short ldsB[2][BN * 64];    // 96 KiB @384

    const int tid  = threadIdx.x;
    const int wave = tid >> 6;
    const int lane = tid & 63;
    const int wm = wave >> 2;           // 0..1 (M, 128 rows each)
    const int wn = wave & 3;            // 0..3 (N, WNS cols each)
    const int g  = lane >> 4;           // k-chunk group 0..3
    const int ro = lane & 15;

    // T1: bijective XCD swizzle (nwg % 8 == 0)
    const int nwg = gridDim.x * gridDim.y;
    int lin = blockIdx.y * gridDim.x + blockIdx.x;
    lin = (lin & 7) * (nwg >> 3) + (lin >> 3);
    const int brow = (lin % gridDim.x) * 256;
    const int bcol = (lin / gridDim.x) * BN;
    const int NT = K >> 6;              // K-tiles of 64

    const unsigned short* As = A  + (size_t)brow * K;
    const unsigned short* Bs = Bm + (size_t)bcol * K;

    f32x4 acc[8][NFR] = {};

    auto stageA = [&](int T) {
        const int buf = T & 1;
        #pragma unroll
        for (int j = 0; j < 4; ++j) {
            const int slot = j * 512 + tid;
            const int row = slot >> 3, c = slot & 7;
            __builtin_amdgcn_global_load_lds(
                (const __attribute__((address_space(1))) void*)(
                    As + (size_t)row * K + T * 64 + ((c ^ (row & 7)) << 3)),
                (__attribute__((address_space(3))) void*)(
                    &ldsA[buf][(j * 512 + wave * 64) * 8]),
                16, 0, 0);
        }
    };
    auto stageB = [&](int T) {
        const int buf = T & 1;
        #pragma unroll
        for (int j = 0; j < BCH / 512; ++j) {
            const int slot = j * 512 + tid;
            const int row = slot >> 3, c = slot & 7;
            __builtin_amdgcn_global_load_lds(
                (const __attribute__((address_space(1))) void*)(
                    Bs + (size_t)row * K + T * 64 + ((c ^ (row & 7)) << 3)),
                (__attribute__((address_space(3))) void*)(
                    &ldsB[buf][(j * 512 + wave * 64) * 8]),
                16, 0, 0);
        }
    };

    auto rdA = [&](int buf, int mi, int ks) -> bf16x8 {
        const int row = wm * 128 + mi * 16 + ro;
        return *reinterpret_cast<const bf16x8*>(
            &ldsA[buf][row * 64 + (((ks * 4 + g) ^ (row & 7)) << 3)]);
    };
    auto rdB = [&](int buf, int ni, int ks) -> bf16x8 {
        const int row = wn * WNS + ni * 16 + ro;
        return *reinterpret_cast<const bf16x8*>(
            &ldsB[buf][row * 64 + (((ks * 4 + g) ^ (row & 7)) << 3)]);
    };

    // prologue (FIFO order): B(0), A(0), B(1)
    stageB(0);
    stageA(0);
    stageB(1);
    asm volatile("s_waitcnt vmcnt(6)" ::: "memory");
    __builtin_amdgcn_s_barrier();

    for (int T = 0; T < NT; ++T) {
        const int buf = T & 1;
        bf16x8 bfr[NFR];

        // ---- ph0: (mq0, ks0), read B(ks0), stage A(T+1) ----
        #pragma unroll
        for (int i = 0; i < NFR; ++i) bfr[i] = rdB(buf, i, 0);
        if (T + 1 < NT) stageA(T + 1);
        __builtin_amdgcn_s_barrier();
        __builtin_amdgcn_s_setprio(1);
        #pragma unroll
        for (int mi = 0; mi < 4; ++mi) {
            bf16x8 af = rdA(buf, mi, 0);
            #pragma unroll
            for (int ni = 0; ni < NFR; ++ni)
                acc[mi][ni] = __builtin_amdgcn_mfma_f32_16x16x32_bf16(af, bfr[ni], acc[mi][ni], 0, 0, 0);
        }
        __builtin_amdgcn_s_setprio(0);
        __builtin_amdgcn_s_barrier();

        // ---- ph1: (mq1, ks0) ----
        __builtin_amdgcn_s_setprio(1);
        #pragma unroll
        for (int mi = 0; mi < 4; ++mi) {
            bf16x8 af = rdA(buf, 4 + mi, 0);
            #pragma unroll
            for (int ni = 0; ni < NFR; ++ni)
                acc[4 + mi][ni] = __builtin_amdgcn_mfma_f32_16x16x32_bf16(af, bfr[ni], acc[4 + mi][ni], 0, 0, 0);
        }
        __builtin_amdgcn_s_setprio(0);
        __builtin_amdgcn_s_barrier();

        // ---- ph2: (mq0, ks1), read B(ks1) ----
        #pragma unroll
        for (int i = 0; i < NFR; ++i) bfr[i] = rdB(buf, i, 1);
        __builtin_amdgcn_s_barrier();
        __builtin_amdgcn_s_setprio(1);
        #pragma unroll
        for (int mi = 0; mi < 4; ++mi) {
            bf16x8 af = rdA(buf, mi, 1);
            #pragma unroll
            for (int ni = 0; ni < NFR; ++ni)
                acc[mi][ni] = __builtin_amdgcn_mfma_f32_16x16x32_bf16(af, bfr[ni], acc[mi][ni], 0, 0, 0);
        }
        __builtin_amdgcn_s_setprio(0);
        __builtin_amdgcn_s_barrier();

        // ---- ph3: (mq1, ks1), stage B(T+2), counted vmcnt ----
        if (T + 2 < NT) stageB(T + 2);
        if (T + 1 < NT) {
            if (T + 2 < NT) asm volatile("s_waitcnt vmcnt(6)" ::: "memory");
            else            asm volatile("s_waitcnt vmcnt(0)" ::: "memory");
        }
        __builtin_amdgcn_s_setprio(1);
        #pragma unroll
        for (int mi = 0; mi < 4; ++mi) {
            bf16x8 af = rdA(buf, 4 + mi, 1);
            #pragma unroll
            for (int ni = 0; ni < NFR; ++ni)
                acc[4 + mi][ni] = __builtin_amdgcn_mfma_f32_16x16x32_bf16(af, bfr[ni], acc[4 + mi][ni], 0, 0, 0);
        }
        __builtin_amdgcn_s_setprio(0);
        __builtin_amdgcn_s_barrier();
    }

    // epilogue: C/D layout col=lane&15, row=(lane>>4)*4+reg  (m89-verified)
    const int rg = g * 4;
    #pragma unroll
    for (int mi = 0; mi < 8; ++mi) {
        #pragma unroll
        for (int r = 0; r < 4; ++r) {
            const int row = brow + wm * 128 + mi * 16 + rg + r;
            const size_t base = (size_t)row * N + bcol + wn * WNS;
            #pragma unroll
            for (int ni = 0; ni < NFR; ++ni) {
                float v = acc[mi][ni][r];
                if constexpr (sizeof(OutT) == 2) C[base + ni * 16 + ro] = f2bf(v);
                else                             C[base + ni * 16 + ro] = v;
            }
        }
    }
}

// ========== GEMM v4 (out-proj): r13 PINNED form — BM=128 x BN=256, BK=64 ========
// r15 A/B: un-pinning this kernel cost ~5us; the pinned schedule wins here.
template <typename OutT>
__global__ __launch_bounds__(512) void gemm_v4_k(
    const unsigned short* __restrict__ A,
    const unsigned short* __restrict__ Bm,
    OutT* __restrict__ C,
    int M, int N, int K)
{
    constexpr int ATILE = 128 * 64;
    constexpr int BTILE = 256 * 64;
    __shared__ __align__(16) unsigned short ldsA[3 * ATILE];
    __shared__ __align__(16) unsigned short ldsB[3 * BTILE];

    const int tid  = threadIdx.x;
    const int wave = tid >> 6;
    const int lane = tid & 63;
    const int wm = wave >> 2;
    const int wn = wave & 3;
    const int g  = lane >> 4;
    const int ro = lane & 15;

    const int nwg = gridDim.x * gridDim.y;
    int lin = blockIdx.y * gridDim.x + blockIdx.x;
    lin = (lin & 7) * (nwg >> 3) + (lin >> 3);
    const int brow = (lin % gridDim.x) * 128;
    const int bcol = (lin / gridDim.x) * 256;
    const int NT = K >> 6;

    const unsigned short* As = A  + (size_t)brow * K;
    const unsigned short* Bs = Bm + (size_t)bcol * K;

    f32x4 acc[4][4] = {};

    auto stage = [&](int buf, int t) {
        #pragma unroll
        for (int j = 0; j < 2; ++j) {
            const int slot = j * 512 + tid;
            const int row = slot >> 3, c = slot & 7;
            __builtin_amdgcn_global_load_lds(
                (const __attribute__((address_space(1))) void*)(
                    As + (size_t)row * K + t * 64 + ((c ^ (row & 7)) << 3)),
                (__attribute__((address_space(3))) void*)(
                    ldsA + buf * ATILE + (j * 512 + wave * 64) * 8),
                16, 0, 0);
        }
        #pragma unroll
        for (int j = 0; j < 4; ++j) {
            const int slot = j * 512 + tid;
            const int row = slot >> 3, c = slot & 7;
            __builtin_amdgcn_global_load_lds(
                (const __attribute__((address_space(1))) void*)(
                    Bs + (size_t)row * K + t * 64 + ((c ^ (row & 7)) << 3)),
                (__attribute__((address_space(3))) void*)(
                    ldsB + buf * BTILE + (j * 512 + wave * 64) * 8),
                16, 0, 0);
        }
    };

    auto rdA = [&](int buf, int mi, int ks) -> bf16x8 {
        const int row = wm * 64 + mi * 16 + ro;
        const int c = (ks * 4 + g) ^ (row & 7);
        return *reinterpret_cast<const bf16x8*>(ldsA + buf * ATILE + row * 64 + c * 8);
    };
    auto rdB = [&](int buf, int ni, int ks) -> bf16x8 {
        const int row = wn * 64 + ni * 16 + ro;
        const int c = (ks * 4 + g) ^ (row & 7);
        return *reinterpret_cast<const bf16x8*>(ldsB + buf * BTILE + row * 64 + c * 8);
    };

    stage(0, 0);
    stage(1, 1);
    asm volatile("s_waitcnt vmcnt(6)" ::: "memory");
    __builtin_amdgcn_s_barrier();

    int cb = 0;
    for (int t = 0; t < NT; ++t) {
        #pragma unroll
        for (int ks = 0; ks < 2; ++ks) {
            bf16x8 af[4], bf[4];
            #pragma unroll
            for (int i = 0; i < 4; ++i) af[i] = rdA(cb, i, ks);
            #pragma unroll
            for (int i = 0; i < 4; ++i) bf[i] = rdB(cb, i, ks);
            if (ks == 0) {
                if (t + 2 < NT) stage((cb == 0) ? 2 : cb - 1, t + 2);
            } else {
                if (t + 2 < NT) asm volatile("s_waitcnt vmcnt(6)" ::: "memory");
                else            asm volatile("s_waitcnt vmcnt(0)" ::: "memory");
            }
            __builtin_amdgcn_s_barrier();
            asm volatile("s_waitcnt lgkmcnt(0)" ::: "memory");
            __builtin_amdgcn_sched_barrier(0);
            __builtin_amdgcn_s_setprio(1);
            #pragma unroll
            for (int mi = 0; mi < 4; ++mi)
                #pragma unroll
                for (int ni = 0; ni < 4; ++ni)
                    acc[mi][ni] = __builtin_amdgcn_mfma_f32_16x16x32_bf16(
                        af[mi], bf[ni], acc[mi][ni], 0, 0, 0);
            __builtin_amdgcn_s_setprio(0);
            __builtin_amdgcn_s_barrier();
        }
        cb = (cb == 2) ? 0 : cb + 1;
    }

    const int rg = g * 4;
    #pragma unroll
    for (int mi = 0; mi < 4; ++mi) {
        #pragma unroll
        for (int r = 0; r < 4; ++r) {
            const int row = brow + wm * 64 + mi * 16 + rg + r;
            const size_t base = (size_t)row * N + bcol + wn * 64;
            #pragma unroll
            for (int ni = 0; ni < 4; ++ni) {
                float v = acc[mi][ni][r];
                if constexpr (sizeof(OutT) == 2) C[base + ni * 16 + ro] = f2bf(v);
                else                             C[base + ni * 16 + ro] = v;
            }
        }
    }
}

// ---------------- per-head RMSNorm + RoPE on Q AND K in one launch ----------------
__global__ __launch_bounds__(256) void qk_post2_k(
    const unsigned short* __restrict__ rawQKV, int ld,
    const float* __restrict__ q_scale, const float* __restrict__ k_scale,
    const float* __restrict__ ctab, const float* __restrict__ stab,
    unsigned short* __restrict__ Qb, unsigned short* __restrict__ Kb,
    float inv_scale)
{
    const int isK = blockIdx.y;
    const unsigned short* raw = rawQKV + (isK ? D_DIM : 0);
    const float* wscale = isK ? k_scale : q_scale;
    unsigned short* outp = isK ? Kb : Qb;
    const float post_mul = isK ? 1.0f : inv_scale;

    const int gw = blockIdx.x * 4 + (threadIdx.x >> 6);
    const int lane = threadIdx.x & 63;
    const int m = gw >> 4;
    const int h = gw & 15;
    const int s = m >> 1, b = m & 1;
    const int c0 = lane * 2;

    const unsigned short* src = raw + (size_t)m * ld + h * C_DIM + c0;
    unsigned int packed = *reinterpret_cast<const unsigned int*>(src);
    float x0 = bf2f((unsigned short)(packed & 0xFFFF));
    float x1 = bf2f((unsigned short)(packed >> 16));

    float ss = x0 * x0 + x1 * x1;
    #pragma unroll
    for (int off = 32; off; off >>= 1) ss += __shfl_xor(ss, off);
    const float rs = rsqrtf(ss * (1.0f / C_DIM) + 1e-6f);

    float n0 = x0 * rs * wscale[c0];
    float n1 = x1 * rs * wscale[c0 + 1];
    float p0 = __shfl_xor(n0, 32);
    float p1 = __shfl_xor(n1, 32);
    const float sgn = (lane < 32) ? -1.0f : 1.0f;
    const float* cp = ctab + (size_t)s * C_DIM + c0;
    const float* sp = stab + (size_t)s * C_DIM + c0;
    float o0 = (n0 * cp[0] + sgn * p0 * sp[0]) * post_mul;
    float o1 = (n1 * cp[1] + sgn * p1 * sp[1]) * post_mul;

    unsigned int opk = (unsigned int)f2bf(o0) | ((unsigned int)f2bf(o1) << 16);
    *reinterpret_cast<unsigned int*>(
        outp + ((size_t)(b * H_DIM + h) * S_DIM + s) * C_DIM + c0) = opk;
}

// ---------------- V relayout+transpose -> Vt [b*H+h][C][S] ----------------
__global__ __launch_bounds__(256) void v_transpose_k(
    const unsigned short* __restrict__ raw, int ld, int colbase,
    unsigned short* __restrict__ Vt)
{
    __shared__ __align__(16) unsigned short tile[64][136];  // +8 pad
    const int bh = blockIdx.y;
    const int b = bh >> 4, h = bh & 15;
    const int sbase = blockIdx.x * 64;
    const int t = threadIdx.x;

    {
        const int s = t >> 2, cq = (t & 3) * 32;
        const unsigned short* src = raw + (size_t)((sbase + s) * B_DIM + b) * ld + colbase + h * C_DIM + cq;
        #pragma unroll
        for (int j = 0; j < 4; ++j) {
            u16x8 v = *reinterpret_cast<const u16x8*>(src + j * 8);
            *reinterpret_cast<u16x8*>(&tile[s][cq + j * 8]) = v;
        }
    }
    __syncthreads();
    {
        const int c = t >> 1, sh = (t & 1) * 32;
        unsigned short* dst = Vt + ((size_t)bh * C_DIM + c) * S_DIM + sbase + sh;
        #pragma unroll
        for (int j = 0; j < 32; j += 8) {
            u16x8 o;
            #pragma unroll
            for (int e = 0; e < 8; ++e) o[e] = tile[sh + j + e][c];
            *reinterpret_cast<u16x8*>(dst + j) = o;
        }
    }
}

// ---------------- flash attention v8: swapped QK^T, KVBLK=128, 160KB LDS -------
__global__ __launch_bounds__(512, 1) void attn_k(
    const unsigned short* __restrict__ Qb,
    const unsigned short* __restrict__ Kb,
    const unsigned short* __restrict__ Vt,
    unsigned short* __restrict__ Ao)          // [M][D], row = s*B+b, col = h*C+c
{
    __shared__ __align__(16) unsigned short ldsK[2][128 * 128];  // 64 KiB
    __shared__ __align__(16) unsigned short ldsV[2][128 * 128];  // 64 KiB
    __shared__ __align__(16) unsigned short plds[8][32 * 64];    // 32 KiB

    const int bh = blockIdx.y;
    const int wave = threadIdx.x >> 6;
    const int lane = threadIdx.x & 63;
    const int qbase = blockIdx.x * 256 + wave * 32;
    const int g  = lane >> 4;
    const int ro = lane & 15;
    const int ko = g * 8;
    const int rg = g * 4;

    const unsigned short* Q  = Qb + (size_t)bh * S_DIM * C_DIM;
    const unsigned short* Km = Kb + (size_t)bh * S_DIM * C_DIM;
    const unsigned short* V  = Vt + (size_t)bh * C_DIM * S_DIM;
    unsigned short* pw = &plds[wave][0];

    bf16x8 qf[2][4];
    #pragma unroll
    for (int mq = 0; mq < 2; ++mq)
        #pragma unroll
        for (int kf = 0; kf < 4; ++kf)
            qf[mq][kf] = *reinterpret_cast<const bf16x8*>(
                Q + (size_t)(qbase + mq * 16 + ro) * C_DIM + kf * 32 + ko);

    bf16x8 ones;
    #pragma unroll
    for (int e = 0; e < 8; ++e) ones[e] = (__bf16)1.0f;

    auto stage = [&](int bufi, int kb) {
        #pragma unroll
        for (int j = 0; j < 4; ++j) {
            const int idx = (wave * 4 + j) * 64 + lane;
            const int row = idx >> 4, ch = idx & 15;
            const int sch = (ch & 8) | ((ch ^ row) & 7);
            __builtin_amdgcn_global_load_lds(
                (const __attribute__((address_space(1))) void*)(
                    Km + (size_t)(kb + row) * C_DIM + sch * 8),
                (__attribute__((address_space(3))) void*)(
                    &ldsK[bufi][(wave * 4 + j) * 512]),
                16, 0, 0);
            __builtin_amdgcn_global_load_lds(
                (const __attribute__((address_space(1))) void*)(
                    V + (size_t)row * S_DIM + kb + sch * 8),
                (__attribute__((address_space(3))) void*)(
                    &ldsV[bufi][(wave * 4 + j) * 512]),
                16, 0, 0);
        }
    };

    f32x4 of[2][8] = {};
    f32x4 osum[2] = {};
    float mrow[2] = {-1e30f, -1e30f};

    stage(0, 0);
    asm volatile("s_waitcnt vmcnt(0)" ::: "memory");
    __syncthreads();

    int cur = 0;
    for (int kb = 0; kb < S_DIM; kb += 128) {
        if (kb + 128 < S_DIM) stage(cur ^ 1, kb + 128);

        // ---- QK^T swapped: s4[mq][nc][r] = S[q=mq*16+ro][kv=nc*16+4g+r] ----
        f32x4 s4[2][8] = {};
        __builtin_amdgcn_s_setprio(1);
        #pragma unroll
        for (int nc = 0; nc < 8; ++nc) {
            const int r_loc = nc * 16 + ro;
            bf16x8 kfr[4];
            #pragma unroll
            for (int kf = 0; kf < 4; ++kf) {
                const int c = kf * 4 + g;
                const int sch = (c & 8) | ((c ^ r_loc) & 7);
                kfr[kf] = *reinterpret_cast<const bf16x8*>(&ldsK[cur][r_loc * 128 + sch * 8]);
            }
            #pragma unroll
            for (int mq = 0; mq < 2; ++mq)
                #pragma unroll
                for (int kf = 0; kf < 4; ++kf)
                    s4[mq][nc] = __builtin_amdgcn_mfma_f32_16x16x32_bf16(
                        kfr[kf], qf[mq][kf], s4[mq][nc], 0, 0, 0);
        }
        __builtin_amdgcn_s_setprio(0);

        // ---- per-lane row max ----
        float mx[2];
        #pragma unroll
        for (int mq = 0; mq < 2; ++mq) {
            float m0 = fmaxf(fmaxf(s4[mq][0][0], s4[mq][0][1]), fmaxf(s4[mq][0][2], s4[mq][0][3]));
            #pragma unroll
            for (int nc = 1; nc < 8; ++nc) {
                float mn = fmaxf(fmaxf(s4[mq][nc][0], s4[mq][nc][1]),
                                 fmaxf(s4[mq][nc][2], s4[mq][nc][3]));
                m0 = fmaxf(m0, mn);
            }
            m0 = fmaxf(m0, __shfl_xor(m0, 16));
            m0 = fmaxf(m0, __shfl_xor(m0, 32));
            mx[mq] = m0;
        }

        // ---- defer-max: rescale rarely; broadcast per-q factors via shfl ----
        if (__any(fmaxf(mx[0] - mrow[0], mx[1] - mrow[1]) > 8.0f)) {
            #pragma unroll
            for (int mq = 0; mq < 2; ++mq) {
                float mnew = fmaxf(mrow[mq], mx[mq]);
                float dm = mrow[mq] - mnew;
                mrow[mq] = mnew;
                #pragma unroll
                for (int r = 0; r < 4; ++r) {
                    float dr = __shfl(dm, (lane & 48) | (rg + r));
                    float rs = __expf(dr);
                    osum[mq][r] *= rs;
                    #pragma unroll
                    for (int nf = 0; nf < 8; ++nf) of[mq][nf][r] *= rs;
                }
            }
        }

        // ---- per kv-half: P -> per-wave LDS (sequential reuse) -> PV ----
        #pragma unroll
        for (int h = 0; h < 2; ++h) {
            #pragma unroll
            for (int mq = 0; mq < 2; ++mq) {
                const int qrow = mq * 16 + ro;
                #pragma unroll
                for (int ncl = 0; ncl < 4; ++ncl) {
                    u16x4 pk;
                    #pragma unroll
                    for (int r = 0; r < 4; ++r)
                        pk[r] = f2bf(__expf(s4[mq][4 * h + ncl][r] - mrow[mq]));
                    const int chunk = 2 * ncl + (g >> 1);
                    *reinterpret_cast<u16x4*>(
                        &pw[qrow * 64 + ((chunk ^ (ro & 7)) << 3) + 4 * (g & 1)]) = pk;
                }
            }
            __asm__ volatile("" ::: "memory");

            __builtin_amdgcn_s_setprio(1);
            #pragma unroll
            for (int ksl = 0; ksl < 2; ++ksl) {
                bf16x8 pa[2];
                #pragma unroll
                for (int mq = 0; mq < 2; ++mq) {
                    const int qrow = mq * 16 + ro;
                    pa[mq] = *reinterpret_cast<const bf16x8*>(
                        &pw[qrow * 64 + (((ksl * 4 + g) ^ (ro & 7)) << 3)]);
                }
                const int ksg = h * 2 + ksl;   // global 32-kv slice 0..3
                #pragma unroll
                for (int nf = 0; nf < 8; ++nf) {
                    const int vr = nf * 16 + ro;
                    const int c2 = ksg * 4 + g;
                    const int sch = (c2 & 8) | ((c2 ^ vr) & 7);
                    bf16x8 vf = *reinterpret_cast<const bf16x8*>(&ldsV[cur][vr * 128 + sch * 8]);
                    #pragma unroll
                    for (int mq = 0; mq < 2; ++mq)
                        of[mq][nf] = __builtin_amdgcn_mfma_f32_16x16x32_bf16(pa[mq], vf, of[mq][nf], 0, 0, 0);
                }
                #pragma unroll
                for (int mq = 0; mq < 2; ++mq)
                    osum[mq] = __builtin_amdgcn_mfma_f32_16x16x32_bf16(pa[mq], ones, osum[mq], 0, 0, 0);
            }
            __builtin_amdgcn_s_setprio(0);
            __asm__ volatile("" ::: "memory");
        }

        asm volatile("s_waitcnt vmcnt(0)" ::: "memory");
        __syncthreads();
        cur ^= 1;
    }

    const int b = bh >> 4, h = bh & 15;
    #pragma unroll
    for (int mq = 0; mq < 2; ++mq) {
        #pragma unroll
        for (int r = 0; r < 4; ++r) {
            const float inv_l = 1.0f / osum[mq][r];
            const int srow = qbase + mq * 16 + rg + r;
            unsigned short* dst = Ao + (size_t)(srow * B_DIM + b) * D_DIM + h * C_DIM;
            #pragma unroll
            for (int nf = 0; nf < 8; ++nf)
                dst[nf * 16 + ro] = f2bf(of[mq][nf][r] * inv_l);
        }
    }
}

extern "C" void kernel_launch(void* const* d_in, const int* in_sizes, int n_in,
                              void* d_out, int out_size, void* d_ws, size_t ws_size,
                              hipStream_t stream) {
    const float* x       = (const float*)d_in[0];
    const float* rope    = (const float*)d_in[1];
    const float* Wq      = (const float*)d_in[2];
    const float* Wk      = (const float*)d_in[3];
    const float* Wv      = (const float*)d_in[4];
    const float* Wo      = (const float*)d_in[5];
    const float* q_scale = (const float*)d_in[6];
    const float* k_scale = (const float*)d_in[7];
    float* out = (float*)d_out;

    char* w = (char*)d_ws;
    size_t off = 0;
    auto alloc = [&](size_t bytes) {
        char* p = w + off; off += (bytes + 255) & ~(size_t)255; return p;
    };
    unsigned short* xb   = (unsigned short*)alloc((size_t)M_DIM * D_DIM * 2);      // 16 MiB
    unsigned short* Wqb  = (unsigned short*)alloc((size_t)4 * D_DIM * D_DIM * 2);  // Wq|Wk|Wv|Wo
    unsigned short* Wob  = Wqb + (size_t)3 * D_DIM * D_DIM;
    unsigned short* rawQKV = (unsigned short*)alloc((size_t)M_DIM * 3 * D_DIM * 2); // [M][6144]
    unsigned short* Qb   = (unsigned short*)alloc((size_t)M_DIM * D_DIM * 2);
    unsigned short* Kb   = (unsigned short*)alloc((size_t)M_DIM * D_DIM * 2);
    unsigned short* Vt   = (unsigned short*)alloc((size_t)M_DIM * D_DIM * 2);
    float* ctab = (float*)alloc((size_t)S_DIM * C_DIM * 4);
    float* stab = (float*)alloc((size_t)S_DIM * C_DIM * 4);
    unsigned short* Ao = rawQKV;  // reuse (rawQKV dead before attention writes)
    (void)ws_size; (void)in_sizes; (void)n_in; (void)out_size;

    const int NQKV = 3 * D_DIM;  // 6144
    const float inv_scale = 0.08838834764831845f;  // 1/sqrt(128)

    cast_all_k<<<2048, 256, 0, stream>>>(x, Wq, Wk, Wv, Wo, rope, xb, Wqb, ctab, stab);

    // fused QKV projection: [4096,2048] x [6144,2048]^T  (256x384 tiles, 16x16=256 blocks EXACT)
    gemm8_k<unsigned short, 384><<<dim3(M_DIM / 256, NQKV / 384), 512, 0, stream>>>(
        xb, Wqb, rawQKV, M_DIM, NQKV, D_DIM);

    qk_post2_k<<<dim3(M_DIM * H_DIM / 4, 2), 256, 0, stream>>>(
        rawQKV, NQKV, q_scale, k_scale, ctab, stab, Qb, Kb, inv_scale);
    v_transpose_k<<<dim3(S_DIM / 64, B_DIM * H_DIM), 256, 0, stream>>>(rawQKV, NQKV, 2 * D_DIM, Vt);

    attn_k<<<dim3(S_DIM / 256, B_DIM * H_DIM), 512, 0, stream>>>(Qb, Kb, Vt, Ao);

    // out projection: [4096,2048] x [2048,2048]^T -> fp32 d_out  (256 blocks exact fill)
    gemm_v4_k<float><<<dim3(M_DIM / 128, D_DIM / 256), 512, 0, stream>>>(
        Ao, Wob, out, M_DIM, D_DIM, D_DIM);
}

// Round 19
// 285.735 us; speedup vs baseline: 1.0382x; 1.0116x over previous
//
#include <hip/hip_runtime.h>
#include <stdint.h>

#define S_DIM 2048
#define B_DIM 2
#define D_DIM 2048
#define H_DIM 16
#define C_DIM 128
#define M_DIM 4096   // S*B rows, row = s*B + b

typedef __bf16 bf16x8 __attribute__((ext_vector_type(8)));
typedef float f32x4 __attribute__((ext_vector_type(4)));
typedef unsigned short u16x4 __attribute__((ext_vector_type(4)));
typedef unsigned short u16x8 __attribute__((ext_vector_type(8)));

__device__ __forceinline__ float bf2f(unsigned short u) {
    union { unsigned int i; float f; } c; c.i = ((unsigned int)u) << 16; return c.f;
}
__device__ __forceinline__ unsigned short f2bf(float f) {
    union { float f; unsigned int i; } c; c.f = f;
    unsigned int r = c.i + 0x7FFFu + ((c.i >> 16) & 1u);  // RTN-even
    return (unsigned short)(r >> 16);
}

// ------- x + 4 weight matrices fp32->bf16 + RoPE cos/sin tables, ONE launch -------
__global__ void cast_all_k(const float* __restrict__ x,
                           const float* __restrict__ w0, const float* __restrict__ w1,
                           const float* __restrict__ w2, const float* __restrict__ w3,
                           const float* __restrict__ freqs,
                           unsigned short* __restrict__ xb, unsigned short* __restrict__ wb,
                           float* __restrict__ ctab, float* __restrict__ stab) {
    const int nx4 = (M_DIM * D_DIM) / 4;   // 2 * 2^20
    const int nw4 = (D_DIM * D_DIM) / 4;   // 2^20
    const int nr4 = (S_DIM * C_DIM) / 4;   // 65536
    const int total = nx4 + 4 * nw4 + nr4;
    int stride = gridDim.x * blockDim.x;
    for (int i = blockIdx.x * blockDim.x + threadIdx.x; i < total; i += stride) {
        if (i < nx4 + 4 * nw4) {
            const float* src; unsigned short* dst; int idx;
            if (i < nx4) { src = x; dst = xb; idx = i; }
            else {
                int j = i - nx4;
                int sel = j >> 20;
                idx = j & (nw4 - 1);
                src = (sel == 0) ? w0 : (sel == 1) ? w1 : (sel == 2) ? w2 : w3;
                dst = wb + (size_t)sel * (size_t)D_DIM * D_DIM;
            }
            float4 v = reinterpret_cast<const float4*>(src)[idx];
            ushort4 o;
            o.x = f2bf(v.x); o.y = f2bf(v.y); o.z = f2bf(v.z); o.w = f2bf(v.w);
            reinterpret_cast<ushort4*>(dst)[idx] = o;
        } else {
            const int j = i - nx4 - 4 * nw4;
            float4 f = reinterpret_cast<const float4*>(freqs)[j];
            float4 cv, sv;
            cv.x = cosf(f.x); cv.y = cosf(f.y); cv.z = cosf(f.z); cv.w = cosf(f.w);
            sv.x = sinf(f.x); sv.y = sinf(f.y); sv.z = sinf(f.z); sv.w = sinf(f.w);
            reinterpret_cast<float4*>(ctab)[j] = cv;
            reinterpret_cast<float4*>(stab)[j] = sv;
        }
    }
}

// ========== GEMM (QKV): r13 form (verified 107us x3) — BM=256 x BN=384, BK=64 ===
// B-frag reads before the phase barrier; A-frag reads INSIDE the MFMA cluster
// (compiler-managed lgkmcnt interleave). stageA whole at ph0, stageB at ph3.
// r14 (pinning) and r17 (spread staging) both regressed — do not perturb.
template <typename OutT, int BN>
__global__ __launch_bounds__(512) void gemm8_k(
    const unsigned short* __restrict__ A,
    const unsigned short* __restrict__ Bm,
    OutT* __restrict__ C,
    int M, int N, int K)
{
    constexpr int NFR = BN / 64;        // n-frags per wave (6 for BN=384)
    constexpr int WNS = BN / 4;         // per-wave n span (96)
    constexpr int BCH = BN / 64 * 512;  // B chunks per tile (3072 for 384)
    __shared__ __align__(16) unsigned short ldsA[2][256 * 64];   // 64 KiB
    __shared__ __align__(16) unsigned short ldsB[2][BN * 64];    // 96 KiB @384

    const int tid  = threadIdx.x;
    const int wave = tid >> 6;
    const int lane = tid & 63;
    const int wm = wave >> 2;           // 0..1 (M, 128 rows each)
    const int wn = wave & 3;            // 0..3 (N, WNS cols each)
    const int g  = lane >> 4;           // k-chunk group 0..3
    const int ro = lane & 15;

    // T1: bijective XCD swizzle (nwg % 8 == 0)
    const int nwg = gridDim.x * gridDim.y;
    int lin = blockIdx.y * gridDim.x + blockIdx.x;
    lin = (lin & 7) * (nwg >> 3) + (lin >> 3);
    const int brow = (lin % gridDim.x) * 256;
    const int bcol = (lin / gridDim.x) * BN;
    const int NT = K >> 6;              // K-tiles of 64

    const unsigned short* As = A  + (size_t)brow * K;
    const unsigned short* Bs = Bm + (size_t)bcol * K;

    f32x4 acc[8][NFR] = {};

    auto stageA = [&](int T) {
        const int buf = T & 1;
        #pragma unroll
        for (int j = 0; j < 4; ++j) {
            const int slot = j * 512 + tid;
            const int row = slot >> 3, c = slot & 7;
            __builtin_amdgcn_global_load_lds(
                (const __attribute__((address_space(1))) void*)(
                    As + (size_t)row * K + T * 64 + ((c ^ (row & 7)) << 3)),
                (__attribute__((address_space(3))) void*)(
                    &ldsA[buf][(j * 512 + wave * 64) * 8]),
                16, 0, 0);
        }
    };
    auto stageB = [&](int T) {
        const int buf = T & 1;
        #pragma unroll
        for (int j = 0; j < BCH / 512; ++j) {
            const int slot = j * 512 + tid;
            const int row = slot >> 3, c = slot & 7;
            __builtin_amdgcn_global_load_lds(
                (const __attribute__((address_space(1))) void*)(
                    Bs + (size_t)row * K + T * 64 + ((c ^ (row & 7)) << 3)),
                (__attribute__((address_space(3))) void*)(
                    &ldsB[buf][(j * 512 + wave * 64) * 8]),
                16, 0, 0);
        }
    };

    auto rdA = [&](int buf, int mi, int ks) -> bf16x8 {
        const int row = wm * 128 + mi * 16 + ro;
        return *reinterpret_cast<const bf16x8*>(
            &ldsA[buf][row * 64 + (((ks * 4 + g) ^ (row & 7)) << 3)]);
    };
    auto rdB = [&](int buf, int ni, int ks) -> bf16x8 {
        const int row = wn * WNS + ni * 16 + ro;
        return *reinterpret_cast<const bf16x8*>(
            &ldsB[buf][row * 64 + (((ks * 4 + g) ^ (row & 7)) << 3)]);
    };

    // prologue (FIFO order): B(0), A(0), B(1)
    stageB(0);
    stageA(0);
    stageB(1);
    asm volatile("s_waitcnt vmcnt(6)" ::: "memory");
    __builtin_amdgcn_s_barrier();

    for (int T = 0; T < NT; ++T) {
        const int buf = T & 1;
        bf16x8 bfr[NFR];

        // ---- ph0: (mq0, ks0), read B(ks0), stage A(T+1) ----
        #pragma unroll
        for (int i = 0; i < NFR; ++i) bfr[i] = rdB(buf, i, 0);
        if (T + 1 < NT) stageA(T + 1);
        __builtin_amdgcn_s_barrier();
        __builtin_amdgcn_s_setprio(1);
        #pragma unroll
        for (int mi = 0; mi < 4; ++mi) {
            bf16x8 af = rdA(buf, mi, 0);
            #pragma unroll
            for (int ni = 0; ni < NFR; ++ni)
                acc[mi][ni] = __builtin_amdgcn_mfma_f32_16x16x32_bf16(af, bfr[ni], acc[mi][ni], 0, 0, 0);
        }
        __builtin_amdgcn_s_setprio(0);
        __builtin_amdgcn_s_barrier();

        // ---- ph1: (mq1, ks0) ----
        __builtin_amdgcn_s_setprio(1);
        #pragma unroll
        for (int mi = 0; mi < 4; ++mi) {
            bf16x8 af = rdA(buf, 4 + mi, 0);
            #pragma unroll
            for (int ni = 0; ni < NFR; ++ni)
                acc[4 + mi][ni] = __builtin_amdgcn_mfma_f32_16x16x32_bf16(af, bfr[ni], acc[4 + mi][ni], 0, 0, 0);
        }
        __builtin_amdgcn_s_setprio(0);
        __builtin_amdgcn_s_barrier();

        // ---- ph2: (mq0, ks1), read B(ks1) ----
        #pragma unroll
        for (int i = 0; i < NFR; ++i) bfr[i] = rdB(buf, i, 1);
        __builtin_amdgcn_s_barrier();
        __builtin_amdgcn_s_setprio(1);
        #pragma unroll
        for (int mi = 0; mi < 4; ++mi) {
            bf16x8 af = rdA(buf, mi, 1);
            #pragma unroll
            for (int ni = 0; ni < NFR; ++ni)
                acc[mi][ni] = __builtin_amdgcn_mfma_f32_16x16x32_bf16(af, bfr[ni], acc[mi][ni], 0, 0, 0);
        }
        __builtin_amdgcn_s_setprio(0);
        __builtin_amdgcn_s_barrier();

        // ---- ph3: (mq1, ks1), stage B(T+2), counted vmcnt ----
        if (T + 2 < NT) stageB(T + 2);
        if (T + 1 < NT) {
            if (T + 2 < NT) asm volatile("s_waitcnt vmcnt(6)" ::: "memory");
            else            asm volatile("s_waitcnt vmcnt(0)" ::: "memory");
        }
        __builtin_amdgcn_s_setprio(1);
        #pragma unroll
        for (int mi = 0; mi < 4; ++mi) {
            bf16x8 af = rdA(buf, 4 + mi, 1);
            #pragma unroll
            for (int ni = 0; ni < NFR; ++ni)
                acc[4 + mi][ni] = __builtin_amdgcn_mfma_f32_16x16x32_bf16(af, bfr[ni], acc[4 + mi][ni], 0, 0, 0);
        }
        __builtin_amdgcn_s_setprio(0);
        __builtin_amdgcn_s_barrier();
    }

    // epilogue: C/D layout col=lane&15, row=(lane>>4)*4+reg  (m89-verified)
    const int rg = g * 4;
    #pragma unroll
    for (int mi = 0; mi < 8; ++mi) {
        #pragma unroll
        for (int r = 0; r < 4; ++r) {
            const int row = brow + wm * 128 + mi * 16 + rg + r;
            const size_t base = (size_t)row * N + bcol + wn * WNS;
            #pragma unroll
            for (int ni = 0; ni < NFR; ++ni) {
                float v = acc[mi][ni][r];
                if constexpr (sizeof(OutT) == 2) C[base + ni * 16 + ro] = f2bf(v);
                else                             C[base + ni * 16 + ro] = v;
            }
        }
    }
}

// ========== GEMM v4 (out-proj): r13 PINNED form — BM=128 x BN=256, BK=64 ========
// r15 A/B: un-pinning this kernel cost ~5us; the pinned schedule wins here.
template <typename OutT>
__global__ __launch_bounds__(512) void gemm_v4_k(
    const unsigned short* __restrict__ A,
    const unsigned short* __restrict__ Bm,
    OutT* __restrict__ C,
    int M, int N, int K)
{
    constexpr int ATILE = 128 * 64;
    constexpr int BTILE = 256 * 64;
    __shared__ __align__(16) unsigned short ldsA[3 * ATILE];
    __shared__ __align__(16) unsigned short ldsB[3 * BTILE];

    const int tid  = threadIdx.x;
    const int wave = tid >> 6;
    const int lane = tid & 63;
    const int wm = wave >> 2;
    const int wn = wave & 3;
    const int g  = lane >> 4;
    const int ro = lane & 15;

    const int nwg = gridDim.x * gridDim.y;
    int lin = blockIdx.y * gridDim.x + blockIdx.x;
    lin = (lin & 7) * (nwg >> 3) + (lin >> 3);
    const int brow = (lin % gridDim.x) * 128;
    const int bcol = (lin / gridDim.x) * 256;
    const int NT = K >> 6;

    const unsigned short* As = A  + (size_t)brow * K;
    const unsigned short* Bs = Bm + (size_t)bcol * K;

    f32x4 acc[4][4] = {};

    auto stage = [&](int buf, int t) {
        #pragma unroll
        for (int j = 0; j < 2; ++j) {
            const int slot = j * 512 + tid;
            const int row = slot >> 3, c = slot & 7;
            __builtin_amdgcn_global_load_lds(
                (const __attribute__((address_space(1))) void*)(
                    As + (size_t)row * K + t * 64 + ((c ^ (row & 7)) << 3)),
                (__attribute__((address_space(3))) void*)(
                    ldsA + buf * ATILE + (j * 512 + wave * 64) * 8),
                16, 0, 0);
        }
        #pragma unroll
        for (int j = 0; j < 4; ++j) {
            const int slot = j * 512 + tid;
            const int row = slot >> 3, c = slot & 7;
            __builtin_amdgcn_global_load_lds(
                (const __attribute__((address_space(1))) void*)(
                    Bs + (size_t)row * K + t * 64 + ((c ^ (row & 7)) << 3)),
                (__attribute__((address_space(3))) void*)(
                    ldsB + buf * BTILE + (j * 512 + wave * 64) * 8),
                16, 0, 0);
        }
    };

    auto rdA = [&](int buf, int mi, int ks) -> bf16x8 {
        const int row = wm * 64 + mi * 16 + ro;
        const int c = (ks * 4 + g) ^ (row & 7);
        return *reinterpret_cast<const bf16x8*>(ldsA + buf * ATILE + row * 64 + c * 8);
    };
    auto rdB = [&](int buf, int ni, int ks) -> bf16x8 {
        const int row = wn * 64 + ni * 16 + ro;
        const int c = (ks * 4 + g) ^ (row & 7);
        return *reinterpret_cast<const bf16x8*>(ldsB + buf * BTILE + row * 64 + c * 8);
    };

    stage(0, 0);
    stage(1, 1);
    asm volatile("s_waitcnt vmcnt(6)" ::: "memory");
    __builtin_amdgcn_s_barrier();

    int cb = 0;
    for (int t = 0; t < NT; ++t) {
        #pragma unroll
        for (int ks = 0; ks < 2; ++ks) {
            bf16x8 af[4], bf[4];
            #pragma unroll
            for (int i = 0; i < 4; ++i) af[i] = rdA(cb, i, ks);
            #pragma unroll
            for (int i = 0; i < 4; ++i) bf[i] = rdB(cb, i, ks);
            if (ks == 0) {
                if (t + 2 < NT) stage((cb == 0) ? 2 : cb - 1, t + 2);
            } else {
                if (t + 2 < NT) asm volatile("s_waitcnt vmcnt(6)" ::: "memory");
                else            asm volatile("s_waitcnt vmcnt(0)" ::: "memory");
            }
            __builtin_amdgcn_s_barrier();
            asm volatile("s_waitcnt lgkmcnt(0)" ::: "memory");
            __builtin_amdgcn_sched_barrier(0);
            __builtin_amdgcn_s_setprio(1);
            #pragma unroll
            for (int mi = 0; mi < 4; ++mi)
                #pragma unroll
                for (int ni = 0; ni < 4; ++ni)
                    acc[mi][ni] = __builtin_amdgcn_mfma_f32_16x16x32_bf16(
                        af[mi], bf[ni], acc[mi][ni], 0, 0, 0);
            __builtin_amdgcn_s_setprio(0);
            __builtin_amdgcn_s_barrier();
        }
        cb = (cb == 2) ? 0 : cb + 1;
    }

    const int rg = g * 4;
    #pragma unroll
    for (int mi = 0; mi < 4; ++mi) {
        #pragma unroll
        for (int r = 0; r < 4; ++r) {
            const int row = brow + wm * 64 + mi * 16 + rg + r;
            const size_t base = (size_t)row * N + bcol + wn * 64;
            #pragma unroll
            for (int ni = 0; ni < 4; ++ni) {
                float v = acc[mi][ni][r];
                if constexpr (sizeof(OutT) == 2) C[base + ni * 16 + ro] = f2bf(v);
                else                             C[base + ni * 16 + ro] = v;
            }
        }
    }
}

// ------- fused post-GEMM: RMSNorm+RoPE on Q,K  AND  V transpose, ONE launch -------
// blocks [0, 32768): qk path (i&1 = isK, i>>1 = bx); blocks [32768, 33792):
// v-transpose path (j = i-32768: sbase = (j&31)*64, bh = j>>5). Both read only
// rawQKV; independent -> safe to co-dispatch, tails overlap.
__global__ __launch_bounds__(256) void post_gemm_k(
    const unsigned short* __restrict__ rawQKV, int ld,
    const float* __restrict__ q_scale, const float* __restrict__ k_scale,
    const float* __restrict__ ctab, const float* __restrict__ stab,
    unsigned short* __restrict__ Qb, unsigned short* __restrict__ Kb,
    unsigned short* __restrict__ Vt, float inv_scale)
{
    if (blockIdx.x < 32768) {
        const int isK = blockIdx.x & 1;
        const int bx = blockIdx.x >> 1;
        const unsigned short* raw = rawQKV + (isK ? D_DIM : 0);
        const float* wscale = isK ? k_scale : q_scale;
        unsigned short* outp = isK ? Kb : Qb;
        const float post_mul = isK ? 1.0f : inv_scale;

        const int gw = bx * 4 + (threadIdx.x >> 6);
        const int lane = threadIdx.x & 63;
        const int m = gw >> 4;
        const int h = gw & 15;
        const int s = m >> 1, b = m & 1;
        const int c0 = lane * 2;

        const unsigned short* src = raw + (size_t)m * ld + h * C_DIM + c0;
        unsigned int packed = *reinterpret_cast<const unsigned int*>(src);
        float x0 = bf2f((unsigned short)(packed & 0xFFFF));
        float x1 = bf2f((unsigned short)(packed >> 16));

        float ss = x0 * x0 + x1 * x1;
        #pragma unroll
        for (int off = 32; off; off >>= 1) ss += __shfl_xor(ss, off);
        const float rs = rsqrtf(ss * (1.0f / C_DIM) + 1e-6f);

        float n0 = x0 * rs * wscale[c0];
        float n1 = x1 * rs * wscale[c0 + 1];
        float p0 = __shfl_xor(n0, 32);
        float p1 = __shfl_xor(n1, 32);
        const float sgn = (lane < 32) ? -1.0f : 1.0f;
        const float* cp = ctab + (size_t)s * C_DIM + c0;
        const float* sp = stab + (size_t)s * C_DIM + c0;
        float o0 = (n0 * cp[0] + sgn * p0 * sp[0]) * post_mul;
        float o1 = (n1 * cp[1] + sgn * p1 * sp[1]) * post_mul;

        unsigned int opk = (unsigned int)f2bf(o0) | ((unsigned int)f2bf(o1) << 16);
        *reinterpret_cast<unsigned int*>(
            outp + ((size_t)(b * H_DIM + h) * S_DIM + s) * C_DIM + c0) = opk;
    } else {
        __shared__ __align__(16) unsigned short tile[64][136];  // +8 pad
        const int j = blockIdx.x - 32768;
        const int bh = j >> 5;
        const int b = bh >> 4, h = bh & 15;
        const int sbase = (j & 31) * 64;
        const int t = threadIdx.x;
        const unsigned short* raw = rawQKV + 2 * D_DIM;  // V columns

        {
            const int s = t >> 2, cq = (t & 3) * 32;
            const unsigned short* src = raw + (size_t)((sbase + s) * B_DIM + b) * ld + h * C_DIM + cq;
            #pragma unroll
            for (int jj = 0; jj < 4; ++jj) {
                u16x8 v = *reinterpret_cast<const u16x8*>(src + jj * 8);
                *reinterpret_cast<u16x8*>(&tile[s][cq + jj * 8]) = v;
            }
        }
        __syncthreads();
        {
            const int c = t >> 1, sh = (t & 1) * 32;
            unsigned short* dst = Vt + ((size_t)bh * C_DIM + c) * S_DIM + sbase + sh;
            #pragma unroll
            for (int jj = 0; jj < 32; jj += 8) {
                u16x8 o;
                #pragma unroll
                for (int e = 0; e < 8; ++e) o[e] = tile[sh + jj + e][c];
                *reinterpret_cast<u16x8*>(dst + jj) = o;
            }
        }
    }
}

// ---------------- flash attention v8: swapped QK^T, KVBLK=128, 160KB LDS -------
__global__ __launch_bounds__(512, 1) void attn_k(
    const unsigned short* __restrict__ Qb,
    const unsigned short* __restrict__ Kb,
    const unsigned short* __restrict__ Vt,
    unsigned short* __restrict__ Ao)          // [M][D], row = s*B+b, col = h*C+c
{
    __shared__ __align__(16) unsigned short ldsK[2][128 * 128];  // 64 KiB
    __shared__ __align__(16) unsigned short ldsV[2][128 * 128];  // 64 KiB
    __shared__ __align__(16) unsigned short plds[8][32 * 64];    // 32 KiB

    const int bh = blockIdx.y;
    const int wave = threadIdx.x >> 6;
    const int lane = threadIdx.x & 63;
    const int qbase = blockIdx.x * 256 + wave * 32;
    const int g  = lane >> 4;
    const int ro = lane & 15;
    const int ko = g * 8;
    const int rg = g * 4;

    const unsigned short* Q  = Qb + (size_t)bh * S_DIM * C_DIM;
    const unsigned short* Km = Kb + (size_t)bh * S_DIM * C_DIM;
    const unsigned short* V  = Vt + (size_t)bh * C_DIM * S_DIM;
    unsigned short* pw = &plds[wave][0];

    bf16x8 qf[2][4];
    #pragma unroll
    for (int mq = 0; mq < 2; ++mq)
        #pragma unroll
        for (int kf = 0; kf < 4; ++kf)
            qf[mq][kf] = *reinterpret_cast<const bf16x8*>(
                Q + (size_t)(qbase + mq * 16 + ro) * C_DIM + kf * 32 + ko);

    bf16x8 ones;
    #pragma unroll
    for (int e = 0; e < 8; ++e) ones[e] = (__bf16)1.0f;

    auto stage = [&](int bufi, int kb) {
        #pragma unroll
        for (int j = 0; j < 4; ++j) {
            const int idx = (wave * 4 + j) * 64 + lane;
            const int row = idx >> 4, ch = idx & 15;
            const int sch = (ch & 8) | ((ch ^ row) & 7);
            __builtin_amdgcn_global_load_lds(
                (const __attribute__((address_space(1))) void*)(
                    Km + (size_t)(kb + row) * C_DIM + sch * 8),
                (__attribute__((address_space(3))) void*)(
                    &ldsK[bufi][(wave * 4 + j) * 512]),
                16, 0, 0);
            __builtin_amdgcn_global_load_lds(
                (const __attribute__((address_space(1))) void*)(
                    V + (size_t)row * S_DIM + kb + sch * 8),
                (__attribute__((address_space(3))) void*)(
                    &ldsV[bufi][(wave * 4 + j) * 512]),
                16, 0, 0);
        }
    };

    f32x4 of[2][8] = {};
    f32x4 osum[2] = {};
    float mrow[2] = {-1e30f, -1e30f};

    stage(0, 0);
    asm volatile("s_waitcnt vmcnt(0)" ::: "memory");
    __syncthreads();

    int cur = 0;
    for (int kb = 0; kb < S_DIM; kb += 128) {
        if (kb + 128 < S_DIM) stage(cur ^ 1, kb + 128);

        // ---- QK^T swapped: s4[mq][nc][r] = S[q=mq*16+ro][kv=nc*16+4g+r] ----
        f32x4 s4[2][8] = {};
        __builtin_amdgcn_s_setprio(1);
        #pragma unroll
        for (int nc = 0; nc < 8; ++nc) {
            const int r_loc = nc * 16 + ro;
            bf16x8 kfr[4];
            #pragma unroll
            for (int kf = 0; kf < 4; ++kf) {
                const int c = kf * 4 + g;
                const int sch = (c & 8) | ((c ^ r_loc) & 7);
                kfr[kf] = *reinterpret_cast<const bf16x8*>(&ldsK[cur][r_loc * 128 + sch * 8]);
            }
            #pragma unroll
            for (int mq = 0; mq < 2; ++mq)
                #pragma unroll
                for (int kf = 0; kf < 4; ++kf)
                    s4[mq][nc] = __builtin_amdgcn_mfma_f32_16x16x32_bf16(
                        kfr[kf], qf[mq][kf], s4[mq][nc], 0, 0, 0);
        }
        __builtin_amdgcn_s_setprio(0);

        // ---- per-lane row max ----
        float mx[2];
        #pragma unroll
        for (int mq = 0; mq < 2; ++mq) {
            float m0 = fmaxf(fmaxf(s4[mq][0][0], s4[mq][0][1]), fmaxf(s4[mq][0][2], s4[mq][0][3]));
            #pragma unroll
            for (int nc = 1; nc < 8; ++nc) {
                float mn = fmaxf(fmaxf(s4[mq][nc][0], s4[mq][nc][1]),
                                 fmaxf(s4[mq][nc][2], s4[mq][nc][3]));
                m0 = fmaxf(m0, mn);
            }
            m0 = fmaxf(m0, __shfl_xor(m0, 16));
            m0 = fmaxf(m0, __shfl_xor(m0, 32));
            mx[mq] = m0;
        }

        // ---- defer-max: rescale rarely; broadcast per-q factors via shfl ----
        if (__any(fmaxf(mx[0] - mrow[0], mx[1] - mrow[1]) > 8.0f)) {
            #pragma unroll
            for (int mq = 0; mq < 2; ++mq) {
                float mnew = fmaxf(mrow[mq], mx[mq]);
                float dm = mrow[mq] - mnew;
                mrow[mq] = mnew;
                #pragma unroll
                for (int r = 0; r < 4; ++r) {
                    float dr = __shfl(dm, (lane & 48) | (rg + r));
                    float rs = __expf(dr);
                    osum[mq][r] *= rs;
                    #pragma unroll
                    for (int nf = 0; nf < 8; ++nf) of[mq][nf][r] *= rs;
                }
            }
        }

        // ---- per kv-half: P -> per-wave LDS (sequential reuse) -> PV ----
        #pragma unroll
        for (int h = 0; h < 2; ++h) {
            #pragma unroll
            for (int mq = 0; mq < 2; ++mq) {
                const int qrow = mq * 16 + ro;
                #pragma unroll
                for (int ncl = 0; ncl < 4; ++ncl) {
                    u16x4 pk;
                    #pragma unroll
                    for (int r = 0; r < 4; ++r)
                        pk[r] = f2bf(__expf(s4[mq][4 * h + ncl][r] - mrow[mq]));
                    const int chunk = 2 * ncl + (g >> 1);
                    *reinterpret_cast<u16x4*>(
                        &pw[qrow * 64 + ((chunk ^ (ro & 7)) << 3) + 4 * (g & 1)]) = pk;
                }
            }
            __asm__ volatile("" ::: "memory");

            __builtin_amdgcn_s_setprio(1);
            #pragma unroll
            for (int ksl = 0; ksl < 2; ++ksl) {
                bf16x8 pa[2];
                #pragma unroll
                for (int mq = 0; mq < 2; ++mq) {
                    const int qrow = mq * 16 + ro;
                    pa[mq] = *reinterpret_cast<const bf16x8*>(
                        &pw[qrow * 64 + (((ksl * 4 + g) ^ (ro & 7)) << 3)]);
                }
                const int ksg = h * 2 + ksl;   // global 32-kv slice 0..3
                #pragma unroll
                for (int nf = 0; nf < 8; ++nf) {
                    const int vr = nf * 16 + ro;
                    const int c2 = ksg * 4 + g;
                    const int sch = (c2 & 8) | ((c2 ^ vr) & 7);
                    bf16x8 vf = *reinterpret_cast<const bf16x8*>(&ldsV[cur][vr * 128 + sch * 8]);
                    #pragma unroll
                    for (int mq = 0; mq < 2; ++mq)
                        of[mq][nf] = __builtin_amdgcn_mfma_f32_16x16x32_bf16(pa[mq], vf, of[mq][nf], 0, 0, 0);
                }
                #pragma unroll
                for (int mq = 0; mq < 2; ++mq)
                    osum[mq] = __builtin_amdgcn_mfma_f32_16x16x32_bf16(pa[mq], ones, osum[mq], 0, 0, 0);
            }
            __builtin_amdgcn_s_setprio(0);
            __asm__ volatile("" ::: "memory");
        }

        asm volatile("s_waitcnt vmcnt(0)" ::: "memory");
        __syncthreads();
        cur ^= 1;
    }

    const int b = bh >> 4, h = bh & 15;
    #pragma unroll
    for (int mq = 0; mq < 2; ++mq) {
        #pragma unroll
        for (int r = 0; r < 4; ++r) {
            const float inv_l = 1.0f / osum[mq][r];
            const int srow = qbase + mq * 16 + rg + r;
            unsigned short* dst = Ao + (size_t)(srow * B_DIM + b) * D_DIM + h * C_DIM;
            #pragma unroll
            for (int nf = 0; nf < 8; ++nf)
                dst[nf * 16 + ro] = f2bf(of[mq][nf][r] * inv_l);
        }
    }
}

extern "C" void kernel_launch(void* const* d_in, const int* in_sizes, int n_in,
                              void* d_out, int out_size, void* d_ws, size_t ws_size,
                              hipStream_t stream) {
    const float* x       = (const float*)d_in[0];
    const float* rope    = (const float*)d_in[1];
    const float* Wq      = (const float*)d_in[2];
    const float* Wk      = (const float*)d_in[3];
    const float* Wv      = (const float*)d_in[4];
    const float* Wo      = (const float*)d_in[5];
    const float* q_scale = (const float*)d_in[6];
    const float* k_scale = (const float*)d_in[7];
    float* out = (float*)d_out;

    char* w = (char*)d_ws;
    size_t off = 0;
    auto alloc = [&](size_t bytes) {
        char* p = w + off; off += (bytes + 255) & ~(size_t)255; return p;
    };
    unsigned short* xb   = (unsigned short*)alloc((size_t)M_DIM * D_DIM * 2);      // 16 MiB
    unsigned short* Wqb  = (unsigned short*)alloc((size_t)4 * D_DIM * D_DIM * 2);  // Wq|Wk|Wv|Wo
    unsigned short* Wob  = Wqb + (size_t)3 * D_DIM * D_DIM;
    unsigned short* rawQKV = (unsigned short*)alloc((size_t)M_DIM * 3 * D_DIM * 2); // [M][6144]
    unsigned short* Qb   = (unsigned short*)alloc((size_t)M_DIM * D_DIM * 2);
    unsigned short* Kb   = (unsigned short*)alloc((size_t)M_DIM * D_DIM * 2);
    unsigned short* Vt   = (unsigned short*)alloc((size_t)M_DIM * D_DIM * 2);
    float* ctab = (float*)alloc((size_t)S_DIM * C_DIM * 4);
    float* stab = (float*)alloc((size_t)S_DIM * C_DIM * 4);
    unsigned short* Ao = rawQKV;  // reuse (rawQKV dead before attention writes)
    (void)ws_size; (void)in_sizes; (void)n_in; (void)out_size;

    const int NQKV = 3 * D_DIM;  // 6144
    const float inv_scale = 0.08838834764831845f;  // 1/sqrt(128)

    cast_all_k<<<2048, 256, 0, stream>>>(x, Wq, Wk, Wv, Wo, rope, xb, Wqb, ctab, stab);

    // fused QKV projection: [4096,2048] x [6144,2048]^T  (256x384 tiles, 16x16=256 blocks EXACT)
    gemm8_k<unsigned short, 384><<<dim3(M_DIM / 256, NQKV / 384), 512, 0, stream>>>(
        xb, Wqb, rawQKV, M_DIM, NQKV, D_DIM);

    // fused RMSNorm+RoPE (Q,K) + V-transpose: 32768 + 1024 blocks, one launch
    post_gemm_k<<<33792, 256, 0, stream>>>(
        rawQKV, NQKV, q_scale, k_scale, ctab, stab, Qb, Kb, Vt, inv_scale);

    attn_k<<<dim3(S_DIM / 256, B_DIM * H_DIM), 512, 0, stream>>>(Qb, Kb, Vt, Ao);

    // out projection: [4096,2048] x [2048,2048]^T -> fp32 d_out  (256 blocks exact fill)
    gemm_v4_k<float><<<dim3(M_DIM / 128, D_DIM / 256), 512, 0, stream>>>(
        Ao, Wob, out, M_DIM, D_DIM, D_DIM);
}